// Round 15
// baseline (714.189 us; speedup 1.0000x reference)
//
#include <hip/hip_runtime.h>
#include <hip/hip_bf16.h>
#include <cstdint>

typedef __attribute__((ext_vector_type(8))) short bf16x8;
typedef __attribute__((ext_vector_type(4))) float f32x4;
typedef __attribute__((ext_vector_type(4))) uint u32x4;

#define LOG2E 1.4426950408889634f
#define SCL2E (0.17677669529663687f * LOG2E)

// ---- workspace layout (bytes) ----
#define WTP_OFF   393216    // after WTq: 196608 ushort
#define BIASP_OFF 524288    // after WTp: 65536 ushort; biasP: 8*49*64 f32 = 100352 B
#define M64G_OFF  624640    // 1024 masks x 49 rows x uint64 = 401408 B (total ws ~1.0 MB)

// ---- LDS layout (bytes), total 51.6 KiB (V and q live in registers) ----
#define XQ_OFF 0        // [50][256] bf16, stride 512 B: x -> attn_out (XOR swizzled)
#define K_OFF  25600    // [50][256] bf16, stride 512 B: k (XOR swizzled)
#define M64_OFF 51200   // 49 x uint64 mask bitmasks
#define LDS_TOTAL 51592

__device__ __forceinline__ ushort f2bf(float f) {
  uint u = __builtin_bit_cast(uint, f);
  u += 0x7fffu + ((u >> 16) & 1u);
  return (ushort)(u >> 16);
}
__device__ __forceinline__ uint cvtpk(float lo, float hi) {
  uint r; asm("v_cvt_pk_bf16_f32 %0, %1, %2" : "=v"(r) : "v"(lo), "v"(hi)); return r;
}
__device__ __forceinline__ float exp2fast(float x) {
  float r; asm("v_exp_f32 %0, %1" : "=v"(r) : "v"(x)); return r;
}
__device__ __forceinline__ float rcpfast(float x) {
  float r; asm("v_rcp_f32 %0, %1" : "=v"(r) : "v"(x)); return r;
}

extern "C" __global__ void wattn_prep(const float* __restrict__ qkv_w,
                                      const float* __restrict__ proj_w,
                                      const float* __restrict__ bt,
                                      const int* __restrict__ mask,
                                      float* __restrict__ biasP,
                                      ushort* __restrict__ WTq,
                                      ushort* __restrict__ WTp,
                                      unsigned long long* __restrict__ M64g) {
  int id = blockIdx.x * 256 + threadIdx.x;
  if (id < 196608) {                     // WTq[oc][ic] = qkv_w[ic][oc]
    int oc = id >> 8, ic = id & 255;
    WTq[id] = f2bf(qkv_w[ic * 768 + oc]);
  }
  if (id < 65536) {                      // WTp[oc][ic] = proj_w[ic][oc]
    int oc = id >> 8, ic = id & 255;
    WTp[id] = f2bf(proj_w[ic * 256 + oc]);
  }
  if (id < 25088) {                      // biasP[h][q][64 padded keys] * log2e
    int h = id / 3136, r = id % 3136, q = r >> 6, key = r & 63;
    float v = 0.f;
    if (key < 49) {
      int dx = (q % 7) - (key % 7);
      int dy = (q / 7) - (key / 7);
      int idx = 13 * (dx + dy + 12);     // reference formula
      if (idx > 168) idx = 168;          // JAX clamps OOB gather
      v = bt[idx * 8 + h] * LOG2E;
    }
    biasP[id] = v;
  }
  if (id < 50176) {                      // M64g[m][r]: bit j = (mask[m][r][j] != 0), j < 49
    int m = id / 49, r = id % 49;
    const int* mp = mask + (size_t)m * 2401 + r * 49;
    unsigned long long bits = 0ull;
    #pragma unroll 7
    for (int j = 0; j < 49; ++j) bits |= (unsigned long long)(mp[j] != 0 ? 1u : 0u) << j;
    M64g[id] = bits;
  }
}

extern "C" __global__ __launch_bounds__(512)
__attribute__((amdgpu_waves_per_eu(4, 4)))   // 128-reg budget; 2 blocks/CU (1a holds 64 AGPR + 64 VGPR = cap)
void wattn_fused(const float* __restrict__ x,
                 const float* __restrict__ qkv_b, const float* __restrict__ proj_b,
                 const ushort* __restrict__ WTq, const ushort* __restrict__ WTp,
                 const float* __restrict__ biasP,
                 const unsigned long long* __restrict__ M64g,
                 float* __restrict__ out) {
  extern __shared__ char lds[];
  const int tid = threadIdx.x;
  const int wid = tid >> 6;    // wave = head
  const int lane = tid & 63;
  const int g = lane >> 4;
  const int c = lane & 15;
  const int h = wid;
  const int w = blockIdx.x;
  const f32x4 zero4 = {0.f, 0.f, 0.f, 0.f};

#define LDX(tt, ks) ({ int row_ = (tt) * 16 + c; if (row_ > 49) row_ = 49;                           \
      *(const bf16x8*)(lds + ((uint)(XQ_OFF + row_ * 512 + ((ks) * 32 + g * 8) * 2) ^               \
                              (((uint)row_ & 7) << 4))); })

  // ================= Phase 0: loads + init + stage =================
  {
    float4 xv0, xv1, xv2, xv3, xv4, xv5, xv6;
    const float4* xb = (const float4*)(x + (size_t)w * 12544);
    xv0 = xb[tid];            xv1 = xb[tid + 512];      xv2 = xb[tid + 1024];
    xv3 = xb[tid + 1536];     xv4 = xb[tid + 2048];     xv5 = xb[tid + 2560];
    if (tid + 3072 < 3136) xv6 = xb[tid + 3072];

    // mask bitmasks: one coalesced 392 B load (precomputed in prep)
    if (tid < 49)
      ((unsigned long long*)(lds + M64_OFF))[tid] = M64g[(size_t)(w & 1023) * 49 + tid];

    uint4 z; z.x = z.y = z.z = z.w = 0;
    if (tid >= 64 && tid < 96) *(uint4*)(lds + XQ_OFF + 49 * 512 + (tid - 64) * 16) = z;
    else if (tid >= 96 && tid < 128) *(uint4*)(lds + K_OFF + 49 * 512 + (tid - 96) * 16) = z;

    // x -> XQ bf16 (swizzled)
#define STX(k, v) { int i = tid + (k) * 512; if ((k) < 6 || i < 3136) {                              \
      int r_ = i >> 6;                                                                               \
      uint off_ = (uint)(XQ_OFF + r_ * 512 + (i & 63) * 8) ^ (((uint)r_ & 7) << 4);                  \
      uint2 u_; u_.x = cvtpk((v).x, (v).y); u_.y = cvtpk((v).z, (v).w);                              \
      *(uint2*)(lds + off_) = u_; } }
    STX(0, xv0) STX(1, xv1) STX(2, xv2) STX(3, xv3) STX(4, xv4) STX(5, xv5) STX(6, xv6)
#undef STX
  }
  __syncthreads();

  u32x4 qpk[4];           // packed q (bf16 pairs), lives into phase 2
  uint2 vpk0[4], vpk1[4]; // packed v (bf16 pairs, swapped layout), lives into phase 2

  // ===== Phase 1a: k = W_k^T x^T (normal); v = x W_v (swapped operands, kept in regs) =====
  // UNCHANGED from verified R11/R14: 64 AGPR acc + ~64 VGPR = at the cap.
  {
    f32x4 acc[4][4];
    #pragma unroll
    for (int j = 0; j < 4; ++j)
      #pragma unroll
      for (int tt = 0; tt < 4; ++tt) acc[j][tt] = zero4;

    #pragma unroll 2
    for (int ks = 0; ks < 8; ++ks) {
      bf16x8 bx[4];
      #pragma unroll
      for (int tt = 0; tt < 4; ++tt) bx[tt] = LDX(tt, ks);
      #pragma unroll
      for (int j = 0; j < 4; ++j) {
        int oc = (j < 2) ? (256 + h * 32 + j * 16) : (512 + h * 32 + (j - 2) * 16);
        bf16x8 wa = *(const bf16x8*)(WTq + (size_t)(oc + c) * 256 + ks * 32 + g * 8);
        if (j < 2) {
          #pragma unroll
          for (int tt = 0; tt < 4; ++tt)
            acc[j][tt] = __builtin_amdgcn_mfma_f32_16x16x32_bf16(wa, bx[tt], acc[j][tt], 0, 0, 0);
        } else {   // swapped: lane (g',c') elem r' = v[tok tt*16+g'*4+r'][d = base+c']
          #pragma unroll
          for (int tt = 0; tt < 4; ++tt)
            acc[j][tt] = __builtin_amdgcn_mfma_f32_16x16x32_bf16(bx[tt], wa, acc[j][tt], 0, 0, 0);
        }
      }
    }
    // epilogue: k -> K region (vectorized)
    f32x4 bk0 = *(const f32x4*)(qkv_b + 256 + h * 32 + g * 4);
    f32x4 bk1 = *(const f32x4*)(qkv_b + 256 + h * 32 + 16 + g * 4);
    #pragma unroll
    for (int tt = 0; tt < 4; ++tt) {
      int tok = tt * 16 + c;
      if (tok < 49) {
        uint swz = ((uint)tok & 7) << 4;
        f32x4 k0 = acc[0][tt] + bk0, k1 = acc[1][tt] + bk1;
        uint2 u0; u0.x = cvtpk(k0[0], k0[1]); u0.y = cvtpk(k0[2], k0[3]);
        uint2 u1; u1.x = cvtpk(k1[0], k1[1]); u1.y = cvtpk(k1[2], k1[3]);
        *(uint2*)(lds + ((uint)(K_OFF + tok * 512 + (h * 32 + g * 4) * 2) ^ swz)) = u0;
        *(uint2*)(lds + ((uint)(K_OFF + tok * 512 + (h * 32 + 16 + g * 4) * 2) ^ swz)) = u1;
      }
    }
    // v -> packed registers (toks >= 49 hold finite bias junk; P is masked to 0 there)
    float bvs0 = qkv_b[512 + h * 32 + c];
    float bvs1 = qkv_b[512 + h * 32 + 16 + c];
    #pragma unroll
    for (int tt = 0; tt < 4; ++tt) {
      f32x4 v0 = acc[2][tt] + bvs0, v1 = acc[3][tt] + bvs1;
      vpk0[tt].x = cvtpk(v0[0], v0[1]); vpk0[tt].y = cvtpk(v0[2], v0[3]);
      vpk1[tt].x = cvtpk(v1[0], v1[1]); vpk1[tt].y = cvtpk(v1[2], v1[3]);
    }
  }

  // ================= Phase 1b: q = W_q^T x^T -> packed registers (full unroll) =================
  {
    f32x4 qa0[4], qa1[4];
    #pragma unroll
    for (int tt = 0; tt < 4; ++tt) { qa0[tt] = zero4; qa1[tt] = zero4; }

    #pragma unroll
    for (int ks = 0; ks < 8; ++ks) {
      bf16x8 bx[4];
      #pragma unroll
      for (int tt = 0; tt < 4; ++tt) bx[tt] = LDX(tt, ks);
      bf16x8 w0 = *(const bf16x8*)(WTq + (size_t)(h * 32 + c) * 256 + ks * 32 + g * 8);
      bf16x8 w1 = *(const bf16x8*)(WTq + (size_t)(h * 32 + 16 + c) * 256 + ks * 32 + g * 8);
      #pragma unroll
      for (int tt = 0; tt < 4; ++tt) {
        qa0[tt] = __builtin_amdgcn_mfma_f32_16x16x32_bf16(w0, bx[tt], qa0[tt], 0, 0, 0);
        qa1[tt] = __builtin_amdgcn_mfma_f32_16x16x32_bf16(w1, bx[tt], qa1[tt], 0, 0, 0);
      }
    }
    f32x4 bq0 = *(const f32x4*)(qkv_b + h * 32 + g * 4) * SCL2E;
    f32x4 bq1 = *(const f32x4*)(qkv_b + h * 32 + 16 + g * 4) * SCL2E;
    #pragma unroll
    for (int tt = 0; tt < 4; ++tt) {
      f32x4 t0 = qa0[tt] * SCL2E + bq0;
      f32x4 t1 = qa1[tt] * SCL2E + bq1;
      qpk[tt][0] = cvtpk(t0[0], t0[1]);
      qpk[tt][1] = cvtpk(t0[2], t0[3]);
      qpk[tt][2] = cvtpk(t1[0], t1[1]);
      qpk[tt][3] = cvtpk(t1[2], t1[3]);
    }
  }
  __syncthreads();   // K visible; all XQ (x) reads complete before attn_out overwrites

  // ================= Phase 2: attention (P, q, V all in registers) =================
  {
    bf16x8 ka[4];
    #pragma unroll
    for (int kt = 0; kt < 4; ++kt) {
      int krow = ((c >> 2) << 3) + ((kt & 1) << 2) + (c & 3) + ((kt >> 1) << 5);
      if (krow > 49) krow = 49;
      uint off = (uint)(K_OFF + krow * 512 + (h * 32 + g * 8) * 2) ^ (((uint)krow & 7) << 4);
      ka[kt] = *(const bf16x8*)(lds + off);
    }
    // hoisted mask words for all 4 qt (phase-0 data; removes per-qt lgkm dependency)
    uint2 m2h[4];
    #pragma unroll
    for (int qt = 0; qt < 4; ++qt) {
      int q = qt * 16 + c;
      int qc = (q < 49) ? q : 48;
      m2h[qt] = *(const uint2*)(lds + M64_OFF + qc * 8);
    }
    // build va[dt][ks] from vpk via same-column shuffles:
    // word m of va[dt][ks]: toks ks*32+g*8+2m..+1; tt = 2ks+(g>>1); src lane = ((g&1)*2+(m>>1))*16+c
    bf16x8 va[2][2];
    {
      const int ghigh = g >> 1;
      const int srcA = ((g & 1) * 2) * 16 + c;
      const int srcB = srcA + 16;
      #pragma unroll
      for (int ks = 0; ks < 2; ++ks) {
        int a0x = __shfl((int)vpk0[2 * ks].x, srcA, 64);
        int a0y = __shfl((int)vpk0[2 * ks].y, srcA, 64);
        int a0xB = __shfl((int)vpk0[2 * ks].x, srcB, 64);
        int a0yB = __shfl((int)vpk0[2 * ks].y, srcB, 64);
        int b0x = __shfl((int)vpk0[2 * ks + 1].x, srcA, 64);
        int b0y = __shfl((int)vpk0[2 * ks + 1].y, srcA, 64);
        int b0xB = __shfl((int)vpk0[2 * ks + 1].x, srcB, 64);
        int b0yB = __shfl((int)vpk0[2 * ks + 1].y, srcB, 64);
        u32x4 w0v = {(uint)(ghigh ? b0x : a0x), (uint)(ghigh ? b0y : a0y),
                     (uint)(ghigh ? b0xB : a0xB), (uint)(ghigh ? b0yB : a0yB)};
        va[0][ks] = __builtin_bit_cast(bf16x8, w0v);
        int a1x = __shfl((int)vpk1[2 * ks].x, srcA, 64);
        int a1y = __shfl((int)vpk1[2 * ks].y, srcA, 64);
        int a1xB = __shfl((int)vpk1[2 * ks].x, srcB, 64);
        int a1yB = __shfl((int)vpk1[2 * ks].y, srcB, 64);
        int b1x = __shfl((int)vpk1[2 * ks + 1].x, srcA, 64);
        int b1y = __shfl((int)vpk1[2 * ks + 1].y, srcA, 64);
        int b1xB = __shfl((int)vpk1[2 * ks + 1].x, srcB, 64);
        int b1yB = __shfl((int)vpk1[2 * ks + 1].y, srcB, 64);
        u32x4 w1v = {(uint)(ghigh ? b1x : a1x), (uint)(ghigh ? b1y : a1y),
                     (uint)(ghigh ? b1xB : a1xB), (uint)(ghigh ? b1yB : a1yB)};
        va[1][ks] = __builtin_bit_cast(bf16x8, w1v);
      }
    }
    const int sA = ((g & 1) << 5) + c;
    const bool glo = (g < 2);

    #pragma unroll   // full unroll: qpk[qt]/m2h[qt] statically indexed
    for (int qt = 0; qt < 4; ++qt) {
      int q = qt * 16 + c;
      int qc = (q < 49) ? q : 48;
      unsigned long long m64 =
          (unsigned long long)m2h[qt].x | ((unsigned long long)(m2h[qt].y | 0xFFFE0000u) << 32);
      int kb[4];
      f32x4 b4[4];
      #pragma unroll
      for (int kt = 0; kt < 4; ++kt) {
        kb[kt] = g * 8 + ((kt & 1) << 2) + ((kt >> 1) << 5);
        b4[kt] = *(const f32x4*)(biasP + (size_t)(h * 49 + qc) * 64 + kb[kt]);
      }
      // q B-fragment via 8 packed shuffles + 4 selects (no LDS)
      int lo0 = __shfl((int)qpk[qt][0], sA, 64);
      int lo1 = __shfl((int)qpk[qt][1], sA, 64);
      int hi0 = __shfl((int)qpk[qt][2], sA, 64);
      int hi1 = __shfl((int)qpk[qt][3], sA, 64);
      int lo0b = __shfl((int)qpk[qt][0], sA + 16, 64);
      int lo1b = __shfl((int)qpk[qt][1], sA + 16, 64);
      int hi0b = __shfl((int)qpk[qt][2], sA + 16, 64);
      int hi1b = __shfl((int)qpk[qt][3], sA + 16, 64);
      u32x4 qw = {(uint)(glo ? lo0 : hi0), (uint)(glo ? lo1 : hi1),
                  (uint)(glo ? lo0b : hi0b), (uint)(glo ? lo1b : hi1b)};
      bf16x8 bqf = __builtin_bit_cast(bf16x8, qw);

      f32x4 s[4];
      #pragma unroll
      for (int kt = 0; kt < 4; ++kt)
        s[kt] = __builtin_amdgcn_mfma_f32_16x16x32_bf16(ka[kt], bqf, zero4, 0, 0, 0);
      #pragma unroll
      for (int kt = 0; kt < 4; ++kt) s[kt] = s[kt] + b4[kt];
      float mx = s[0][0];
      #pragma unroll
      for (int kt = 0; kt < 4; ++kt)
        #pragma unroll
        for (int r = 0; r < 4; ++r) mx = fmaxf(mx, s[kt][r]);
      mx = fmaxf(mx, __shfl_xor(mx, 16));
      mx = fmaxf(mx, __shfl_xor(mx, 32));
      float sum = 0.f;
      #pragma unroll
      for (int kt = 0; kt < 4; ++kt) {
        uint nib = (uint)(m64 >> kb[kt]) & 0xFu;
        #pragma unroll
        for (int r = 0; r < 4; ++r) {
          float e = exp2fast(s[kt][r] - mx);
          e = ((nib >> r) & 1u) ? 0.f : e;   // masked / pad keys -> 0 weight
          s[kt][r] = e;
          sum += e;
        }
      }
      sum += __shfl_xor(sum, 16);
      sum += __shfl_xor(sum, 32);
      float rdn = rcpfast(sum + 1e-30f);
      u32x4 w0 = {cvtpk(s[0][0], s[0][1]), cvtpk(s[0][2], s[0][3]),
                  cvtpk(s[1][0], s[1][1]), cvtpk(s[1][2], s[1][3])};
      u32x4 w1 = {cvtpk(s[2][0], s[2][1]), cvtpk(s[2][2], s[2][3]),
                  cvtpk(s[3][0], s[3][1]), cvtpk(s[3][2], s[3][3])};
      bf16x8 pb0 = __builtin_bit_cast(bf16x8, w0);
      bf16x8 pb1 = __builtin_bit_cast(bf16x8, w1);
      f32x4 o0 = __builtin_amdgcn_mfma_f32_16x16x32_bf16(va[0][0], pb0, zero4, 0, 0, 0);
      o0 = __builtin_amdgcn_mfma_f32_16x16x32_bf16(va[0][1], pb1, o0, 0, 0, 0);
      f32x4 o1 = __builtin_amdgcn_mfma_f32_16x16x32_bf16(va[1][0], pb0, zero4, 0, 0, 0);
      o1 = __builtin_amdgcn_mfma_f32_16x16x32_bf16(va[1][1], pb1, o1, 0, 0, 0);
      if (q < 49) {
        uint swz = ((uint)q & 7) << 4;
        f32x4 v0 = o0 * rdn, v1 = o1 * rdn;
        uint2 u0; u0.x = cvtpk(v0[0], v0[1]); u0.y = cvtpk(v0[2], v0[3]);
        uint2 u1; u1.x = cvtpk(v1[0], v1[1]); u1.y = cvtpk(v1[2], v1[3]);
        *(uint2*)(lds + ((uint)(XQ_OFF + q * 512 + (h * 32 + g * 4) * 2) ^ swz)) = u0;
        *(uint2*)(lds + ((uint)(XQ_OFF + q * 512 + (h * 32 + 16 + g * 4) * 2) ^ swz)) = u1;
      }
    }
  }
  __syncthreads();

  // ================= Phase 3: out^T = Wp^T attn^T (full unroll) =================
  {
    f32x4 pacc[2][4];
    #pragma unroll
    for (int ot = 0; ot < 2; ++ot)
      #pragma unroll
      for (int tt = 0; tt < 4; ++tt) pacc[ot][tt] = zero4;

    #pragma unroll
    for (int ks = 0; ks < 8; ++ks) {
      bf16x8 bx[4];
      #pragma unroll
      for (int tt = 0; tt < 4; ++tt) bx[tt] = LDX(tt, ks);
      #pragma unroll
      for (int ot = 0; ot < 2; ++ot) {
        bf16x8 wp = *(const bf16x8*)(WTp + (size_t)(h * 32 + ot * 16 + c) * 256 + ks * 32 + g * 8);
        #pragma unroll
        for (int tt = 0; tt < 4; ++tt)
          pacc[ot][tt] = __builtin_amdgcn_mfma_f32_16x16x32_bf16(wp, bx[tt], pacc[ot][tt], 0, 0, 0);
      }
    }
    float* ob = out + (size_t)w * 12544;
    #pragma unroll
    for (int ot = 0; ot < 2; ++ot) {
      f32x4 pb = *(const f32x4*)(proj_b + h * 32 + ot * 16 + g * 4);
      #pragma unroll
      for (int tt = 0; tt < 4; ++tt) {
        int tok = tt * 16 + c;
        if (tok < 49) {
          f32x4 r = pacc[ot][tt] + pb;
          *(f32x4*)(ob + tok * 256 + h * 32 + ot * 16 + g * 4) = r;
        }
      }
    }
  }
#undef LDX
}

extern "C" void kernel_launch(void* const* d_in, const int* in_sizes, int n_in,
                              void* d_out, int out_size, void* d_ws, size_t ws_size,
                              hipStream_t stream) {
  const float* x      = (const float*)d_in[0];
  const int*   mask   = (const int*)d_in[1];
  const float* qkv_w  = (const float*)d_in[2];
  const float* qkv_b  = (const float*)d_in[3];
  const float* proj_w = (const float*)d_in[4];
  const float* proj_b = (const float*)d_in[5];
  const float* bt     = (const float*)d_in[6];
  float* out = (float*)d_out;

  ushort* WTq   = (ushort*)d_ws;
  ushort* WTp   = (ushort*)((char*)d_ws + WTP_OFF);
  float*  biasP = (float*)((char*)d_ws + BIASP_OFF);
  unsigned long long* M64g = (unsigned long long*)((char*)d_ws + M64G_OFF);

  hipLaunchKernelGGL(wattn_prep, dim3(768), dim3(256), 0, stream,
                     qkv_w, proj_w, bt, mask, biasP, WTq, WTp, M64g);

  hipFuncSetAttribute(reinterpret_cast<const void*>(wattn_fused),
                      hipFuncAttributeMaxDynamicSharedMemorySize, LDS_TOTAL);
  hipLaunchKernelGGL(wattn_fused, dim3(8192), dim3(512), LDS_TOTAL, stream,
                     x, qkv_b, proj_b, WTq, WTp, biasP, M64g, out);
}

// Round 16
// 652.606 us; speedup vs baseline: 1.0944x; 1.0944x over previous
//
#include <hip/hip_runtime.h>
#include <hip/hip_bf16.h>
#include <cstdint>

typedef __attribute__((ext_vector_type(8))) short bf16x8;
typedef __attribute__((ext_vector_type(4))) float f32x4;
typedef __attribute__((ext_vector_type(4))) uint u32x4;

#define LOG2E 1.4426950408889634f
#define SCL2E (0.17677669529663687f * LOG2E)

// ---- workspace layout (bytes) ----
#define WTP_OFF   393216    // after WTq: 196608 ushort
#define BIASP_OFF 524288    // after WTp: 65536 ushort; biasP: 8*49*64 f32 = 100352 B
#define M64G_OFF  624640    // 1024 masks x 49 rows x uint64 = 401408 B (total ws ~1.0 MB)

// ---- LDS layout (bytes), total 51.6 KiB (V and q live in registers) ----
#define XQ_OFF 0        // [50][256] bf16, stride 512 B: x -> attn_out (XOR swizzled)
#define K_OFF  25600    // [50][256] bf16, stride 512 B: k (XOR swizzled)
#define M64_OFF 51200   // 49 x uint64 mask bitmasks
#define LDS_TOTAL 51592

__device__ __forceinline__ ushort f2bf(float f) {
  uint u = __builtin_bit_cast(uint, f);
  u += 0x7fffu + ((u >> 16) & 1u);
  return (ushort)(u >> 16);
}
__device__ __forceinline__ uint cvtpk(float lo, float hi) {
  uint r; asm("v_cvt_pk_bf16_f32 %0, %1, %2" : "=v"(r) : "v"(lo), "v"(hi)); return r;
}
__device__ __forceinline__ float exp2fast(float x) {
  float r; asm("v_exp_f32 %0, %1" : "=v"(r) : "v"(x)); return r;
}
__device__ __forceinline__ float rcpfast(float x) {
  float r; asm("v_rcp_f32 %0, %1" : "=v"(r) : "v"(x)); return r;
}

extern "C" __global__ void wattn_prep(const float* __restrict__ qkv_w,
                                      const float* __restrict__ proj_w,
                                      const float* __restrict__ bt,
                                      const int* __restrict__ mask,
                                      float* __restrict__ biasP,
                                      ushort* __restrict__ WTq,
                                      ushort* __restrict__ WTp,
                                      unsigned long long* __restrict__ M64g) {
  int id = blockIdx.x * 256 + threadIdx.x;
  if (id < 196608) {                     // WTq[oc][ic] = qkv_w[ic][oc]
    int oc = id >> 8, ic = id & 255;
    WTq[id] = f2bf(qkv_w[ic * 768 + oc]);
  }
  if (id < 65536) {                      // WTp[oc][ic] = proj_w[ic][oc]
    int oc = id >> 8, ic = id & 255;
    WTp[id] = f2bf(proj_w[ic * 256 + oc]);
  }
  if (id < 25088) {                      // biasP[h][q][64 padded keys] * log2e
    int h = id / 3136, r = id % 3136, q = r >> 6, key = r & 63;
    float v = 0.f;
    if (key < 49) {
      int dx = (q % 7) - (key % 7);
      int dy = (q / 7) - (key / 7);
      int idx = 13 * (dx + dy + 12);     // reference formula
      if (idx > 168) idx = 168;          // JAX clamps OOB gather
      v = bt[idx * 8 + h] * LOG2E;
    }
    biasP[id] = v;
  }
  if (id < 50176) {                      // M64g[m][r]: bit j = (mask[m][r][j] != 0), j < 49
    int m = id / 49, r = id % 49;
    const int* mp = mask + (size_t)m * 2401 + r * 49;
    unsigned long long bits = 0ull;
    #pragma unroll 7
    for (int j = 0; j < 49; ++j) bits |= (unsigned long long)(mp[j] != 0 ? 1u : 0u) << j;
    M64g[id] = bits;
  }
}

extern "C" __global__ __launch_bounds__(512)
__attribute__((amdgpu_waves_per_eu(4, 4)))   // 128-reg budget; 2 blocks/CU (1a holds 64 AGPR + 64 VGPR = cap)
void wattn_fused(const float* __restrict__ x,
                 const float* __restrict__ qkv_b, const float* __restrict__ proj_b,
                 const ushort* __restrict__ WTq, const ushort* __restrict__ WTp,
                 const float* __restrict__ biasP,
                 const unsigned long long* __restrict__ M64g,
                 float* __restrict__ out) {
  extern __shared__ char lds[];
  const int tid = threadIdx.x;
  const int wid = tid >> 6;    // wave = head
  const int lane = tid & 63;
  const int g = lane >> 4;
  const int c = lane & 15;
  const int h = wid;
  const int w = blockIdx.x;
  const f32x4 zero4 = {0.f, 0.f, 0.f, 0.f};

#define LDX(tt, ks) ({ int row_ = (tt) * 16 + c; if (row_ > 49) row_ = 49;                           \
      *(const bf16x8*)(lds + ((uint)(XQ_OFF + row_ * 512 + ((ks) * 32 + g * 8) * 2) ^               \
                              (((uint)row_ & 7) << 4))); })

  // ================= Phase 0: loads + init + stage =================
  {
    float4 xv0, xv1, xv2, xv3, xv4, xv5, xv6;
    const float4* xb = (const float4*)(x + (size_t)w * 12544);
    xv0 = xb[tid];            xv1 = xb[tid + 512];      xv2 = xb[tid + 1024];
    xv3 = xb[tid + 1536];     xv4 = xb[tid + 2048];     xv5 = xb[tid + 2560];
    if (tid + 3072 < 3136) xv6 = xb[tid + 3072];

    // mask bitmasks: one coalesced 392 B load (precomputed in prep)
    if (tid < 49)
      ((unsigned long long*)(lds + M64_OFF))[tid] = M64g[(size_t)(w & 1023) * 49 + tid];

    uint4 z; z.x = z.y = z.z = z.w = 0;
    if (tid >= 64 && tid < 96) *(uint4*)(lds + XQ_OFF + 49 * 512 + (tid - 64) * 16) = z;
    else if (tid >= 96 && tid < 128) *(uint4*)(lds + K_OFF + 49 * 512 + (tid - 96) * 16) = z;

    // x -> XQ bf16 (swizzled)
#define STX(k, v) { int i = tid + (k) * 512; if ((k) < 6 || i < 3136) {                              \
      int r_ = i >> 6;                                                                               \
      uint off_ = (uint)(XQ_OFF + r_ * 512 + (i & 63) * 8) ^ (((uint)r_ & 7) << 4);                  \
      uint2 u_; u_.x = cvtpk((v).x, (v).y); u_.y = cvtpk((v).z, (v).w);                              \
      *(uint2*)(lds + off_) = u_; } }
    STX(0, xv0) STX(1, xv1) STX(2, xv2) STX(3, xv3) STX(4, xv4) STX(5, xv5) STX(6, xv6)
#undef STX
  }
  __syncthreads();

  u32x4 qpk[4];           // packed q (bf16 pairs), lives into phase 2
  uint2 vpk0[4], vpk1[4]; // packed v (bf16 pairs, swapped layout), lives into phase 2

  // ===== Phase 1a: k = W_k^T x^T (normal); v = x W_v (swapped operands, kept in regs) =====
  // UNCHANGED from verified R11/R14: 64 AGPR acc + ~64 VGPR = at the cap.
  {
    f32x4 acc[4][4];
    #pragma unroll
    for (int j = 0; j < 4; ++j)
      #pragma unroll
      for (int tt = 0; tt < 4; ++tt) acc[j][tt] = zero4;

    #pragma unroll 2
    for (int ks = 0; ks < 8; ++ks) {
      bf16x8 bx[4];
      #pragma unroll
      for (int tt = 0; tt < 4; ++tt) bx[tt] = LDX(tt, ks);
      #pragma unroll
      for (int j = 0; j < 4; ++j) {
        int oc = (j < 2) ? (256 + h * 32 + j * 16) : (512 + h * 32 + (j - 2) * 16);
        bf16x8 wa = *(const bf16x8*)(WTq + (size_t)(oc + c) * 256 + ks * 32 + g * 8);
        if (j < 2) {
          #pragma unroll
          for (int tt = 0; tt < 4; ++tt)
            acc[j][tt] = __builtin_amdgcn_mfma_f32_16x16x32_bf16(wa, bx[tt], acc[j][tt], 0, 0, 0);
        } else {   // swapped: lane (g',c') elem r' = v[tok tt*16+g'*4+r'][d = base+c']
          #pragma unroll
          for (int tt = 0; tt < 4; ++tt)
            acc[j][tt] = __builtin_amdgcn_mfma_f32_16x16x32_bf16(bx[tt], wa, acc[j][tt], 0, 0, 0);
        }
      }
    }
    // epilogue: k -> K region (vectorized)
    f32x4 bk0 = *(const f32x4*)(qkv_b + 256 + h * 32 + g * 4);
    f32x4 bk1 = *(const f32x4*)(qkv_b + 256 + h * 32 + 16 + g * 4);
    #pragma unroll
    for (int tt = 0; tt < 4; ++tt) {
      int tok = tt * 16 + c;
      if (tok < 49) {
        uint swz = ((uint)tok & 7) << 4;
        f32x4 k0 = acc[0][tt] + bk0, k1 = acc[1][tt] + bk1;
        uint2 u0; u0.x = cvtpk(k0[0], k0[1]); u0.y = cvtpk(k0[2], k0[3]);
        uint2 u1; u1.x = cvtpk(k1[0], k1[1]); u1.y = cvtpk(k1[2], k1[3]);
        *(uint2*)(lds + ((uint)(K_OFF + tok * 512 + (h * 32 + g * 4) * 2) ^ swz)) = u0;
        *(uint2*)(lds + ((uint)(K_OFF + tok * 512 + (h * 32 + 16 + g * 4) * 2) ^ swz)) = u1;
      }
    }
    // v -> packed registers (toks >= 49 hold finite bias junk; P is masked to 0 there)
    float bvs0 = qkv_b[512 + h * 32 + c];
    float bvs1 = qkv_b[512 + h * 32 + 16 + c];
    #pragma unroll
    for (int tt = 0; tt < 4; ++tt) {
      f32x4 v0 = acc[2][tt] + bvs0, v1 = acc[3][tt] + bvs1;
      vpk0[tt].x = cvtpk(v0[0], v0[1]); vpk0[tt].y = cvtpk(v0[2], v0[3]);
      vpk1[tt].x = cvtpk(v1[0], v1[1]); vpk1[tt].y = cvtpk(v1[2], v1[3]);
    }
  }

  // ================= Phase 1b: q = W_q^T x^T -> packed registers =================
  {
    f32x4 qa0[4], qa1[4];
    #pragma unroll
    for (int tt = 0; tt < 4; ++tt) { qa0[tt] = zero4; qa1[tt] = zero4; }

    #pragma unroll 4
    for (int ks = 0; ks < 8; ++ks) {
      bf16x8 bx[4];
      #pragma unroll
      for (int tt = 0; tt < 4; ++tt) bx[tt] = LDX(tt, ks);
      bf16x8 w0 = *(const bf16x8*)(WTq + (size_t)(h * 32 + c) * 256 + ks * 32 + g * 8);
      bf16x8 w1 = *(const bf16x8*)(WTq + (size_t)(h * 32 + 16 + c) * 256 + ks * 32 + g * 8);
      #pragma unroll
      for (int tt = 0; tt < 4; ++tt) {
        qa0[tt] = __builtin_amdgcn_mfma_f32_16x16x32_bf16(w0, bx[tt], qa0[tt], 0, 0, 0);
        qa1[tt] = __builtin_amdgcn_mfma_f32_16x16x32_bf16(w1, bx[tt], qa1[tt], 0, 0, 0);
      }
    }
    f32x4 bq0 = *(const f32x4*)(qkv_b + h * 32 + g * 4) * SCL2E;
    f32x4 bq1 = *(const f32x4*)(qkv_b + h * 32 + 16 + g * 4) * SCL2E;
    #pragma unroll
    for (int tt = 0; tt < 4; ++tt) {
      f32x4 t0 = qa0[tt] * SCL2E + bq0;
      f32x4 t1 = qa1[tt] * SCL2E + bq1;
      qpk[tt][0] = cvtpk(t0[0], t0[1]);
      qpk[tt][1] = cvtpk(t0[2], t0[3]);
      qpk[tt][2] = cvtpk(t1[0], t1[1]);
      qpk[tt][3] = cvtpk(t1[2], t1[3]);
    }
  }
  __syncthreads();   // K visible; all XQ (x) reads complete before attn_out overwrites

  // ================= Phase 2: attention (P, q, V all in registers) =================
  {
    bf16x8 ka[4];
    #pragma unroll
    for (int kt = 0; kt < 4; ++kt) {
      int krow = ((c >> 2) << 3) + ((kt & 1) << 2) + (c & 3) + ((kt >> 1) << 5);
      if (krow > 49) krow = 49;
      uint off = (uint)(K_OFF + krow * 512 + (h * 32 + g * 8) * 2) ^ (((uint)krow & 7) << 4);
      ka[kt] = *(const bf16x8*)(lds + off);
    }
    // hoisted mask words for all 4 qt (phase-0 data; removes per-qt lgkm dependency)
    uint2 m2h[4];
    #pragma unroll
    for (int qt = 0; qt < 4; ++qt) {
      int q = qt * 16 + c;
      int qc = (q < 49) ? q : 48;
      m2h[qt] = *(const uint2*)(lds + M64_OFF + qc * 8);
    }
    // build va[dt][ks] from vpk via same-column shuffles:
    // word m of va[dt][ks]: toks ks*32+g*8+2m..+1; tt = 2ks+(g>>1); src lane = ((g&1)*2+(m>>1))*16+c
    bf16x8 va[2][2];
    {
      const int ghigh = g >> 1;
      const int srcA = ((g & 1) * 2) * 16 + c;
      const int srcB = srcA + 16;
      #pragma unroll
      for (int ks = 0; ks < 2; ++ks) {
        int a0x = __shfl((int)vpk0[2 * ks].x, srcA, 64);
        int a0y = __shfl((int)vpk0[2 * ks].y, srcA, 64);
        int a0xB = __shfl((int)vpk0[2 * ks].x, srcB, 64);
        int a0yB = __shfl((int)vpk0[2 * ks].y, srcB, 64);
        int b0x = __shfl((int)vpk0[2 * ks + 1].x, srcA, 64);
        int b0y = __shfl((int)vpk0[2 * ks + 1].y, srcA, 64);
        int b0xB = __shfl((int)vpk0[2 * ks + 1].x, srcB, 64);
        int b0yB = __shfl((int)vpk0[2 * ks + 1].y, srcB, 64);
        u32x4 w0v = {(uint)(ghigh ? b0x : a0x), (uint)(ghigh ? b0y : a0y),
                     (uint)(ghigh ? b0xB : a0xB), (uint)(ghigh ? b0yB : a0yB)};
        va[0][ks] = __builtin_bit_cast(bf16x8, w0v);
        int a1x = __shfl((int)vpk1[2 * ks].x, srcA, 64);
        int a1y = __shfl((int)vpk1[2 * ks].y, srcA, 64);
        int a1xB = __shfl((int)vpk1[2 * ks].x, srcB, 64);
        int a1yB = __shfl((int)vpk1[2 * ks].y, srcB, 64);
        int b1x = __shfl((int)vpk1[2 * ks + 1].x, srcA, 64);
        int b1y = __shfl((int)vpk1[2 * ks + 1].y, srcA, 64);
        int b1xB = __shfl((int)vpk1[2 * ks + 1].x, srcB, 64);
        int b1yB = __shfl((int)vpk1[2 * ks + 1].y, srcB, 64);
        u32x4 w1v = {(uint)(ghigh ? b1x : a1x), (uint)(ghigh ? b1y : a1y),
                     (uint)(ghigh ? b1xB : a1xB), (uint)(ghigh ? b1yB : a1yB)};
        va[1][ks] = __builtin_bit_cast(bf16x8, w1v);
      }
    }
    const int sA = ((g & 1) << 5) + c;
    const bool glo = (g < 2);

    #pragma unroll   // full unroll: qpk[qt]/m2h[qt] statically indexed
    for (int qt = 0; qt < 4; ++qt) {
      int q = qt * 16 + c;
      int qc = (q < 49) ? q : 48;
      unsigned long long m64 =
          (unsigned long long)m2h[qt].x | ((unsigned long long)(m2h[qt].y | 0xFFFE0000u) << 32);
      int kb[4];
      f32x4 b4[4];
      #pragma unroll
      for (int kt = 0; kt < 4; ++kt) {
        kb[kt] = g * 8 + ((kt & 1) << 2) + ((kt >> 1) << 5);
        b4[kt] = *(const f32x4*)(biasP + (size_t)(h * 49 + qc) * 64 + kb[kt]);
      }
      // q B-fragment via 8 packed shuffles + 4 selects (no LDS)
      int lo0 = __shfl((int)qpk[qt][0], sA, 64);
      int lo1 = __shfl((int)qpk[qt][1], sA, 64);
      int hi0 = __shfl((int)qpk[qt][2], sA, 64);
      int hi1 = __shfl((int)qpk[qt][3], sA, 64);
      int lo0b = __shfl((int)qpk[qt][0], sA + 16, 64);
      int lo1b = __shfl((int)qpk[qt][1], sA + 16, 64);
      int hi0b = __shfl((int)qpk[qt][2], sA + 16, 64);
      int hi1b = __shfl((int)qpk[qt][3], sA + 16, 64);
      u32x4 qw = {(uint)(glo ? lo0 : hi0), (uint)(glo ? lo1 : hi1),
                  (uint)(glo ? lo0b : hi0b), (uint)(glo ? lo1b : hi1b)};
      bf16x8 bqf = __builtin_bit_cast(bf16x8, qw);

      f32x4 s[4];
      #pragma unroll
      for (int kt = 0; kt < 4; ++kt)
        s[kt] = __builtin_amdgcn_mfma_f32_16x16x32_bf16(ka[kt], bqf, zero4, 0, 0, 0);
      #pragma unroll
      for (int kt = 0; kt < 4; ++kt) s[kt] = s[kt] + b4[kt];
      float mx = s[0][0];
      #pragma unroll
      for (int kt = 0; kt < 4; ++kt)
        #pragma unroll
        for (int r = 0; r < 4; ++r) mx = fmaxf(mx, s[kt][r]);
      mx = fmaxf(mx, __shfl_xor(mx, 16));
      mx = fmaxf(mx, __shfl_xor(mx, 32));
      float sum = 0.f;
      #pragma unroll
      for (int kt = 0; kt < 4; ++kt) {
        uint nib = (uint)(m64 >> kb[kt]) & 0xFu;
        #pragma unroll
        for (int r = 0; r < 4; ++r) {
          float e = exp2fast(s[kt][r] - mx);
          e = ((nib >> r) & 1u) ? 0.f : e;   // masked / pad keys -> 0 weight
          s[kt][r] = e;
          sum += e;
        }
      }
      sum += __shfl_xor(sum, 16);
      sum += __shfl_xor(sum, 32);
      float rdn = rcpfast(sum + 1e-30f);
      u32x4 w0 = {cvtpk(s[0][0], s[0][1]), cvtpk(s[0][2], s[0][3]),
                  cvtpk(s[1][0], s[1][1]), cvtpk(s[1][2], s[1][3])};
      u32x4 w1 = {cvtpk(s[2][0], s[2][1]), cvtpk(s[2][2], s[2][3]),
                  cvtpk(s[3][0], s[3][1]), cvtpk(s[3][2], s[3][3])};
      bf16x8 pb0 = __builtin_bit_cast(bf16x8, w0);
      bf16x8 pb1 = __builtin_bit_cast(bf16x8, w1);
      f32x4 o0 = __builtin_amdgcn_mfma_f32_16x16x32_bf16(va[0][0], pb0, zero4, 0, 0, 0);
      o0 = __builtin_amdgcn_mfma_f32_16x16x32_bf16(va[0][1], pb1, o0, 0, 0, 0);
      f32x4 o1 = __builtin_amdgcn_mfma_f32_16x16x32_bf16(va[1][0], pb0, zero4, 0, 0, 0);
      o1 = __builtin_amdgcn_mfma_f32_16x16x32_bf16(va[1][1], pb1, o1, 0, 0, 0);
      if (q < 49) {
        uint swz = ((uint)q & 7) << 4;
        f32x4 v0 = o0 * rdn, v1 = o1 * rdn;
        uint2 u0; u0.x = cvtpk(v0[0], v0[1]); u0.y = cvtpk(v0[2], v0[3]);
        uint2 u1; u1.x = cvtpk(v1[0], v1[1]); u1.y = cvtpk(v1[2], v1[3]);
        *(uint2*)(lds + ((uint)(XQ_OFF + q * 512 + (h * 32 + g * 4) * 2) ^ swz)) = u0;
        *(uint2*)(lds + ((uint)(XQ_OFF + q * 512 + (h * 32 + 16 + g * 4) * 2) ^ swz)) = u1;
      }
    }
  }
  __syncthreads();

  // ================= Phase 3: out^T = Wp^T attn^T =================
  {
    f32x4 pacc[2][4];
    #pragma unroll
    for (int ot = 0; ot < 2; ++ot)
      #pragma unroll
      for (int tt = 0; tt < 4; ++tt) pacc[ot][tt] = zero4;

    #pragma unroll 4
    for (int ks = 0; ks < 8; ++ks) {
      bf16x8 bx[4];
      #pragma unroll
      for (int tt = 0; tt < 4; ++tt) bx[tt] = LDX(tt, ks);
      #pragma unroll
      for (int ot = 0; ot < 2; ++ot) {
        bf16x8 wp = *(const bf16x8*)(WTp + (size_t)(h * 32 + ot * 16 + c) * 256 + ks * 32 + g * 8);
        #pragma unroll
        for (int tt = 0; tt < 4; ++tt)
          pacc[ot][tt] = __builtin_amdgcn_mfma_f32_16x16x32_bf16(wp, bx[tt], pacc[ot][tt], 0, 0, 0);
      }
    }
    float* ob = out + (size_t)w * 12544;
    #pragma unroll
    for (int ot = 0; ot < 2; ++ot) {
      f32x4 pb = *(const f32x4*)(proj_b + h * 32 + ot * 16 + g * 4);
      #pragma unroll
      for (int tt = 0; tt < 4; ++tt) {
        int tok = tt * 16 + c;
        if (tok < 49) {
          f32x4 r = pacc[ot][tt] + pb;
          *(f32x4*)(ob + tok * 256 + h * 32 + ot * 16 + g * 4) = r;
        }
      }
    }
  }
#undef LDX
}

extern "C" void kernel_launch(void* const* d_in, const int* in_sizes, int n_in,
                              void* d_out, int out_size, void* d_ws, size_t ws_size,
                              hipStream_t stream) {
  const float* x      = (const float*)d_in[0];
  const int*   mask   = (const int*)d_in[1];
  const float* qkv_w  = (const float*)d_in[2];
  const float* qkv_b  = (const float*)d_in[3];
  const float* proj_w = (const float*)d_in[4];
  const float* proj_b = (const float*)d_in[5];
  const float* bt     = (const float*)d_in[6];
  float* out = (float*)d_out;

  ushort* WTq   = (ushort*)d_ws;
  ushort* WTp   = (ushort*)((char*)d_ws + WTP_OFF);
  float*  biasP = (float*)((char*)d_ws + BIASP_OFF);
  unsigned long long* M64g = (unsigned long long*)((char*)d_ws + M64G_OFF);

  hipLaunchKernelGGL(wattn_prep, dim3(768), dim3(256), 0, stream,
                     qkv_w, proj_w, bt, mask, biasP, WTq, WTp, M64g);

  hipFuncSetAttribute(reinterpret_cast<const void*>(wattn_fused),
                      hipFuncAttributeMaxDynamicSharedMemorySize, LDS_TOTAL);
  hipLaunchKernelGGL(wattn_fused, dim3(8192), dim3(512), LDS_TOTAL, stream,
                     x, qkv_b, proj_b, WTq, WTp, biasP, M64g, out);
}